// Round 5
// baseline (346.396 us; speedup 1.0000x reference)
//
#include <hip/hip_runtime.h>
#include <stdint.h>

// Match numpy f32 elementwise semantics: no implicit FMA contraction.
#pragma clang fp contract(off)

#define GRIDN 256
#define NC (GRIDN * GRIDN)
#define RESN 512
#define RBLOCKS 256
#define CAP 1024      // per-cell capacity (matches prior verified CAP)
#define NTILE 16384   // 128x128 tiles of 2x2 cells
#define MAXT 2048     // max active tiles binned (observed ~625; 3x headroom)

// NOTE (r1): GLOBAL per-cell RETURNING atomics regressed 154->2403us (projection
// concentrates tris into ~4% of cells -> same-address fetch-add serialization).
// NOTE (r3): row-parallel full-tbox re-stream (1 load/iter, 1 blk/CU) was
// latency-bound: 124us/pass. Fix applied here: uint4 loads (4 tris/load) +
// multiple blocks/CU + wave-aggregated LDS appends (1 atomic/wave/cell).
// NOTE (r5 = this round): active-tile fused binning. Tiles (2x2 cells) flagged
// in setup via LDS-aggregated NON-RETURNING atomicOr; ~625 active tiles each
// get one block that streams tbox once and builds per-cell top-64 lists in LDS.
// Replaces count/scanA1/scanB/place/cellsort (5 kernels -> 2: tiles+bin).

typedef unsigned short bfraw;

__device__ __forceinline__ float bf2f(bfraw h) {
    return __uint_as_float(((uint32_t)h) << 16);   // bf16 upcast is exact
}
__device__ __forceinline__ bfraw f2bf(float f) {
    uint32_t b = __float_as_uint(f);               // RNE f32 -> bf16
    return (bfraw)((b + 0x7FFFu + ((b >> 16) & 1u)) >> 16);
}
__device__ __forceinline__ uint32_t fkey(float f) {
    uint32_t b = __float_as_uint(f);
    return (b & 0x80000000u) ? ~b : (b | 0x80000000u);
}

// ---------------- partial reduce (sum fp64, min/max fp32) + buffer init ---------
// Grid is exactly 256x256 threads: zeroes cellN (NC), tileSlot (16384),
// tileMask (512 words), numActive — all consumed only by later kernels.
__global__ __launch_bounds__(256) void k_reduce1(const bfraw* __restrict__ u, int nrows,
                                                 double* __restrict__ psum,
                                                 float* __restrict__ pmin,
                                                 float* __restrict__ pmax,
                                                 uint32_t* __restrict__ cellN,
                                                 uint32_t* __restrict__ tileSlot,
                                                 uint32_t* __restrict__ tileMask,
                                                 uint32_t* __restrict__ numActive) {
    __shared__ double ssum[256 * 3];
    __shared__ float smin[256 * 3];
    __shared__ float smax[256 * 3];
    int t = threadIdx.x;
    int gid = blockIdx.x * 256 + t;
    cellN[gid] = 0u;                                   // NC entries exactly
    if (blockIdx.x < 64) tileSlot[gid] = 0xFFFFFFFFu;  // 16384 entries
    if (blockIdx.x == 64) { tileMask[t] = 0u; tileMask[t + 256] = 0u; }
    if (blockIdx.x == 65 && t == 0) numActive[0] = 0u;
    double s0 = 0.0, s1 = 0.0, s2 = 0.0;
    float mn0 = INFINITY, mn1 = INFINITY, mn2 = INFINITY;
    float mx0 = -INFINITY, mx1 = -INFINITY, mx2 = -INFINITY;
    for (int r = blockIdx.x * 256 + t; r < nrows; r += 256 * RBLOCKS) {
        float a = bf2f(u[3 * r + 0]);
        float b = bf2f(u[3 * r + 1]);
        float c = bf2f(u[3 * r + 2]);
        s0 += (double)a; s1 += (double)b; s2 += (double)c;
        mn0 = fminf(mn0, a); mx0 = fmaxf(mx0, a);
        mn1 = fminf(mn1, b); mx1 = fmaxf(mx1, b);
        mn2 = fminf(mn2, c); mx2 = fmaxf(mx2, c);
    }
    ssum[t * 3 + 0] = s0; ssum[t * 3 + 1] = s1; ssum[t * 3 + 2] = s2;
    smin[t * 3 + 0] = mn0; smin[t * 3 + 1] = mn1; smin[t * 3 + 2] = mn2;
    smax[t * 3 + 0] = mx0; smax[t * 3 + 1] = mx1; smax[t * 3 + 2] = mx2;
    __syncthreads();
    for (int st = 128; st > 0; st >>= 1) {
        if (t < st) {
            for (int c = 0; c < 3; c++) {
                ssum[t * 3 + c] += ssum[(t + st) * 3 + c];
                smin[t * 3 + c] = fminf(smin[t * 3 + c], smin[(t + st) * 3 + c]);
                smax[t * 3 + c] = fmaxf(smax[t * 3 + c], smax[(t + st) * 3 + c]);
            }
        }
        __syncthreads();
    }
    if (t == 0) {
        for (int c = 0; c < 3; c++) {
            psum[blockIdx.x * 3 + c] = ssum[c];
            pmin[blockIdx.x * 3 + c] = smin[c];
            pmax[blockIdx.x * 3 + c] = smax[c];
        }
    }
}

// ---------------- finalize constants ----------------
__global__ __launch_bounds__(256) void k_reduce2(const double* __restrict__ psum,
                                                 const float* __restrict__ pmin,
                                                 const float* __restrict__ pmax,
                                                 int nrows, float* __restrict__ cst) {
    __shared__ double ssum[256 * 3];
    __shared__ float smin[256 * 3];
    __shared__ float smax[256 * 3];
    int t = threadIdx.x;
    for (int c = 0; c < 3; c++) {
        ssum[t * 3 + c] = psum[t * 3 + c];
        smin[t * 3 + c] = pmin[t * 3 + c];
        smax[t * 3 + c] = pmax[t * 3 + c];
    }
    __syncthreads();
    for (int st = 128; st > 0; st >>= 1) {
        if (t < st) {
            for (int c = 0; c < 3; c++) {
                ssum[t * 3 + c] += ssum[(t + st) * 3 + c];
                smin[t * 3 + c] = fminf(smin[t * 3 + c], smin[(t + st) * 3 + c]);
                smax[t * 3 + c] = fmaxf(smax[t * 3 + c], smax[(t + st) * 3 + c]);
            }
        }
        __syncthreads();
    }
    if (t == 0) {
        float fn = (float)nrows;
        float m0 = (float)ssum[0] / fn;
        float m1 = (float)ssum[1] / fn;
        float m2 = (float)ssum[2] / fn;
        // fp32 rounding is monotone: max_r(u - mean) == colmax - mean exactly.
        float vmax = fmaxf(fmaxf(smax[0] - m0, smax[1] - m1), smax[2] - m2);
        float vmin = fminf(fminf(smin[0] - m0, smin[1] - m1), smin[2] - m2);
        float span = fmaxf(vmax - vmin, 1e-06f);
        float s = 0.5f / span;   // SCALE / span
        cst[0] = m0; cst[1] = m1; cst[2] = m2; cst[3] = s;
    }
}

// ---------------- per-triangle setup + tile flagging ----------------
// tcs layout per tri (8 floats): cpx0,cpy0,cpx1,cpy1,cpx2,cpy2,shade,0
// tbox: lox | loy<<8 | hx<<16 | hy<<24  with hx=min(hix,lox+3), hy=min(hiy,loy+3)
// Tiles (2x2 cells) covered by the bbox are flagged via LDS-aggregated
// NON-RETURNING atomicOr (fire-and-forget pipelines fine, unlike r1's adds).
__global__ __launch_bounds__(256) void k_setup(const bfraw* __restrict__ u,
                                               const int* __restrict__ faces,
                                               const bfraw* __restrict__ mvp,
                                               const bfraw* __restrict__ light,
                                               const float* __restrict__ cst,
                                               int F,
                                               float* __restrict__ tcs,
                                               uint32_t* __restrict__ tz,
                                               uint32_t* __restrict__ tbox,
                                               uint32_t* __restrict__ tileMask) {
    __shared__ uint32_t lbm[512];
    int t = threadIdx.x;
    lbm[t] = 0u; lbm[t + 256] = 0u;
    __syncthreads();
    int f = blockIdx.x * 256 + t;
    if (f < F) {
        float m0 = cst[0], m1 = cst[1], m2 = cst[2], s = cst[3];
        float M[12];
        for (int i = 0; i < 12; i++) M[i] = bf2f(mvp[i]);

        float vx[3], vy[3], vz[3], cpx[3], cpy[3], zc[3];
        for (int j = 0; j < 3; j++) {
            int idx = faces[3 * f + j];
            float a = bf2f(u[3 * idx + 0]);
            float b = bf2f(u[3 * idx + 1]);
            float c = bf2f(u[3 * idx + 2]);
            float x = (a - m0) * s;
            float y = (b - m1) * s;
            float z = (c - m2) * s;
            vx[j] = x; vy[j] = y; vz[j] = z;
            // BLAS-style ascending-k fma chain; w=1 -> plain add of M[row][3]
            float cx = fmaf(x, M[0], 0.0f);
            cx = fmaf(y, M[1], cx); cx = fmaf(z, M[2], cx); cx = cx + M[3];
            float cy = fmaf(x, M[4], 0.0f);
            cy = fmaf(y, M[5], cy); cy = fmaf(z, M[6], cy); cy = cy + M[7];
            float cz = fmaf(x, M[8], 0.0f);
            cz = fmaf(y, M[9], cz); cz = fmaf(z, M[10], cz); cz = cz + M[11];
            cpx[j] = (cx + 1.0f) * 0.5f;
            cpy[j] = (cy + 1.0f) * 0.5f;
            zc[j] = cz;
        }
        float zmean = ((zc[0] + zc[1]) + zc[2]) / 3.0f;

        float e1x = vx[0] - vx[1], e1y = vy[0] - vy[1], e1z = vz[0] - vz[1];
        float e2x = vx[2] - vx[1], e2y = vy[2] - vy[1], e2z = vz[2] - vz[1];
        float nx = e1y * e2z - e1z * e2y;
        float ny = e1z * e2x - e1x * e2z;
        float nz = e1x * e2y - e1y * e2x;
        float nn = nx * nx;
        nn = nn + ny * ny;
        nn = nn + nz * nz;
        float d = sqrtf(nn) + 1e-10f;
        float inx = nx / d, iny = ny / d, inz = nz / d;

        float l0 = bf2f(light[0]), l1 = bf2f(light[1]), l2 = bf2f(light[2]);
        float p0 = (-l0) * inx;
        float p1 = (-l1) * iny;
        float p2 = (-l2) * inz;
        float shading = fmaxf((p0 + p1) + p2, 0.0f);

        tcs[f * 8 + 0] = cpx[0]; tcs[f * 8 + 1] = cpy[0];
        tcs[f * 8 + 2] = cpx[1]; tcs[f * 8 + 3] = cpy[1];
        tcs[f * 8 + 4] = cpx[2]; tcs[f * 8 + 5] = cpy[2];
        tcs[f * 8 + 6] = shading;
        tcs[f * 8 + 7] = 0.0f;

        tz[f] = fkey(zmean);

        float mnx = fminf(fminf(cpx[0], cpx[1]), cpx[2]);
        float mny = fminf(fminf(cpy[0], cpy[1]), cpy[2]);
        float mxx = fmaxf(fmaxf(cpx[0], cpx[1]), cpx[2]);
        float mxy = fmaxf(fmaxf(cpy[0], cpy[1]), cpy[2]);
        int lox = (int)floorf(mnx * 256.0f); lox = lox < 0 ? 0 : (lox > 255 ? 255 : lox);
        int loy = (int)floorf(mny * 256.0f); loy = loy < 0 ? 0 : (loy > 255 ? 255 : loy);
        int hix = (int)floorf(mxx * 256.0f); hix = hix < 0 ? 0 : (hix > 255 ? 255 : hix);
        int hiy = (int)floorf(mxy * 256.0f); hiy = hiy < 0 ? 0 : (hiy > 255 ? 255 : hiy);
        int hx = hix < lox + 3 ? hix : lox + 3;   // SPAN=4 window
        int hy = hiy < loy + 3 ? hiy : loy + 3;
        tbox[f] = (uint32_t)lox | ((uint32_t)loy << 8) | ((uint32_t)hx << 16) | ((uint32_t)hy << 24);

        int tx0 = lox >> 1, tx1 = hx >> 1;
        int ty0 = loy >> 1, ty1 = hy >> 1;
        for (int ty = ty0; ty <= ty1; ty++) {
            for (int tx = tx0; tx <= tx1; tx++) {
                int tl = ty * 128 + tx;
                atomicOr(&lbm[tl >> 5], 1u << (tl & 31));
            }
        }
    }
    __syncthreads();
    uint32_t w0 = lbm[t];       if (w0) atomicOr(&tileMask[t], w0);
    uint32_t w1 = lbm[t + 256]; if (w1) atomicOr(&tileMask[t + 256], w1);
}

// ---------------- compact active tiles (1 block) ----------------
__global__ __launch_bounds__(256) void k_tiles(const uint32_t* __restrict__ tileMask,
                                               uint32_t* __restrict__ tileList,
                                               uint32_t* __restrict__ tileSlot,
                                               uint32_t* __restrict__ numActive) {
    __shared__ uint32_t cnt;
    int t = threadIdx.x;
    if (t == 0) cnt = 0u;
    __syncthreads();
    for (int w = t; w < 512; w += 256) {
        uint32_t m = tileMask[w];
        while (m) {
            int b = __ffs(m) - 1;
            m &= m - 1u;
            uint32_t tile = (uint32_t)w * 32u + (uint32_t)b;
            uint32_t idx = atomicAdd(&cnt, 1u);
            if (idx < MAXT) { tileList[idx] = tile; tileSlot[tile] = idx; }
        }
    }
    __syncthreads();
    if (t == 0) numActive[0] = cnt < MAXT ? cnt : MAXT;
}

// ---------------- fused bin: per-active-tile candidate lists + top-64 ----------
// One block per active 2x2-cell tile. Streams tbox once (uint4 = 4 tris/load),
// wave-ballot-aggregated append into per-cell LDS segments (1 LDS atomic per
// wave per cell), then in-LDS rank-selection of the 64 smallest (zkey,id) for
// cells with n>64 (written SORTED -> raster first-hit), or raw list for n<=64
// (raster argmin). Same sets/caps/selection semantics as the verified pipeline.
__device__ __forceinline__ void emit_tri(uint32_t bx, uint32_t f, bool vld,
                                         int cx0, int cy0,
                                         const uint32_t* __restrict__ tz,
                                         uint64_t (*seg)[CAP],
                                         uint32_t* cur, int lane) {
    int lox = bx & 255, loy = (bx >> 8) & 255;
    int hx = (bx >> 16) & 255, hy = (bx >> 24) & 255;
    bool ov = vld && lox <= cx0 + 1 && hx >= cx0 && loy <= cy0 + 1 && hy >= cy0;
    if (__ballot(ov) == 0ull) return;
    uint64_t key = 0ull;
    if (ov) key = ((uint64_t)tz[f] << 32) | (uint64_t)f;
#pragma unroll
    for (int c = 0; c < 4; c++) {
        int cx = cx0 + (c & 1), cy = cy0 + (c >> 1);
        bool cov = ov && lox <= cx && hx >= cx && loy <= cy && hy >= cy;
        unsigned long long m = __ballot(cov);
        if (m == 0ull) continue;
        int rank = __popcll(m & ((1ull << lane) - 1ull));
        int leader = __ffsll(m) - 1;
        uint32_t bpos = 0u;
        if (lane == leader) bpos = atomicAdd(&cur[c], (uint32_t)__popcll(m));
        bpos = __shfl(bpos, leader);
        if (cov) {
            uint32_t idx = bpos + (uint32_t)rank;
            if (idx < CAP) seg[c][idx] = key;
        }
    }
}

__global__ __launch_bounds__(256) void k_bin(const uint32_t* __restrict__ tbox,
                                             const uint32_t* __restrict__ tz,
                                             const uint32_t* __restrict__ tileList,
                                             const uint32_t* __restrict__ numActive,
                                             uint32_t* __restrict__ cellTop,
                                             uint32_t* __restrict__ cellN,
                                             int F) {
    __shared__ uint64_t seg[4][CAP];   // 32 KB
    __shared__ uint32_t cur[4];
    uint32_t na = numActive[0]; if (na > MAXT) na = MAXT;
    if (blockIdx.x >= na) return;
    uint32_t tile = tileList[blockIdx.x] & (NTILE - 1);
    int ty = (int)(tile >> 7), tx = (int)(tile & 127u);
    int cy0 = ty * 2, cx0 = tx * 2;
    int t = threadIdx.x, lane = t & 63;
    if (t < 4) cur[t] = 0u;
    __syncthreads();

    const uint4* tb4 = (const uint4*)tbox;
    int F4 = F >> 2;
    int nIter = (F4 + 255) / 256;
    for (int i = 0; i < nIter; i++) {
        int f4 = i * 256 + t;
        bool vld = f4 < F4;
        uint4 v = vld ? tb4[f4] : make_uint4(0u, 0u, 0u, 0u);
        uint32_t fb = (uint32_t)f4 * 4u;
        emit_tri(v.x, fb + 0u, vld, cx0, cy0, tz, seg, cur, lane);
        emit_tri(v.y, fb + 1u, vld, cx0, cy0, tz, seg, cur, lane);
        emit_tri(v.z, fb + 2u, vld, cx0, cy0, tz, seg, cur, lane);
        emit_tri(v.w, fb + 3u, vld, cx0, cy0, tz, seg, cur, lane);
    }
    for (int f0 = F4 * 4; f0 < F; f0 += 256) {   // tail (F%4 != 0)
        int f = f0 + t;
        bool vld = f < F;
        uint32_t bx = vld ? tbox[f] : 0u;
        emit_tri(bx, (uint32_t)f, vld, cx0, cy0, tz, seg, cur, lane);
    }
    __syncthreads();

    for (int c = 0; c < 4; c++) {
        uint32_t n = cur[c]; if (n > CAP) n = CAP;
        int cy = cy0 + (c >> 1), cx = cx0 + (c & 1);
        int cell = cy * GRIDN + cx;
        uint32_t ob = blockIdx.x * 256u + (uint32_t)c * 64u;
        if (n <= 64u) {
            if (t < (int)n) cellTop[ob + t] = (uint32_t)(seg[c][t] & 0xFFFFFFFFull);
            if (t == 0) cellN[cell] = n;
        } else {
            uint64_t k0 = ~0ull, k1 = ~0ull, k2 = ~0ull, k3 = ~0ull;
            uint32_t i0 = t, i1 = t + 256, i2 = t + 512, i3 = t + 768;
            if (i0 < n) k0 = seg[c][i0];
            if (i1 < n) k1 = seg[c][i1];
            if (i2 < n) k2 = seg[c][i2];
            if (i3 < n) k3 = seg[c][i3];
            uint32_t r0 = 0, r1 = 0, r2 = 0, r3 = 0;
            for (uint32_t j = 0; j < n; j++) {
                uint64_t kj = seg[c][j];   // broadcast: conflict-free
                r0 += (kj < k0) ? 1u : 0u;
                r1 += (kj < k1) ? 1u : 0u;
                r2 += (kj < k2) ? 1u : 0u;
                r3 += (kj < k3) ? 1u : 0u;
            }
            if (i0 < n && r0 < 64u) cellTop[ob + r0] = (uint32_t)(k0 & 0xFFFFFFFFull);
            if (i1 < n && r1 < 64u) cellTop[ob + r1] = (uint32_t)(k1 & 0xFFFFFFFFull);
            if (i2 < n && r2 < 64u) cellTop[ob + r2] = (uint32_t)(k2 & 0xFFFFFFFFull);
            if (i3 < n && r3 < 64u) cellTop[ob + r3] = (uint32_t)(k3 & 0xFFFFFFFFull);
            if (t == 0) cellN[cell] = 64u | 256u;   // sorted flag
        }
    }
}

// ---------------- raster: first-hit (sorted cells) / argmin (small cells) -------
__global__ __launch_bounds__(256) void k_raster(const float* __restrict__ tcs,
                                                const uint32_t* __restrict__ tz,
                                                const uint32_t* __restrict__ tileSlot,
                                                const uint32_t* __restrict__ cellN,
                                                const uint32_t* __restrict__ cellTop,
                                                const bfraw* __restrict__ basec,
                                                const bfraw* __restrict__ bg,
                                                bfraw* __restrict__ out, int F) {
    int p = blockIdx.x * 256 + threadIdx.x;
    int col = p & (RESN - 1);
    int row = p >> 9;
    float px = ((float)col + 0.5f) / 512.0f;
    float py = ((float)row + 0.5f) / 512.0f;
    int cell = (row >> 1) * GRIDN + (col >> 1);
    int t_id = (row >> 2) * 128 + (col >> 2);
    uint32_t slot = tileSlot[t_id];
    uint32_t n = 0u, base = 0u;
    bool srt = false;
    if (slot < MAXT) {
        uint32_t nf = cellN[cell];
        n = nf & 0xFFu; if (n > 64u) n = 64u;
        srt = (nf & 256u) != 0u;
        int c = ((row >> 1) & 1) * 2 + ((col >> 1) & 1);
        base = slot * 256u + (uint32_t)c * 64u;
    }
    uint64_t best = ~0ull;
    uint32_t bestId = 0u;
    float bestSh = 0.0f;
    bool found = false;
    for (uint32_t k = 0; k < n; k++) {
        uint32_t id = cellTop[base + k];
        if (id >= (uint32_t)F) continue;   // defensive
        const float4 A = *(const float4*)(tcs + (size_t)id * 8);
        const float4 B = *(const float4*)(tcs + (size_t)id * 8 + 4);
        float ax = A.x, ay = A.y, bx = A.z, by = A.w, cx = B.x, cy = B.y;
        float e0 = (bx - ax) * (py - ay) - (by - ay) * (px - ax);
        float e1 = (cx - bx) * (py - by) - (cy - by) * (px - bx);
        float e2 = (ax - cx) * (py - cy) - (ay - cy) * (px - cx);
        bool inside = (e0 >= 0.0f && e1 >= 0.0f && e2 >= 0.0f) ||
                      (e0 <= 0.0f && e1 <= 0.0f && e2 <= 0.0f);
        if (inside) {
            if (srt) {   // sorted: first hit is THE hit
                bestId = id; bestSh = B.z; found = true;
                break;
            }
            uint64_t key = ((uint64_t)tz[id] << 32) | id;
            if (key < best) { best = key; bestId = id; bestSh = B.z; found = true; }
        }
    }
    float r, g, b;
    if (found) {
        r = bf2f(basec[3 * bestId + 0]) * bestSh;
        g = bf2f(basec[3 * bestId + 1]) * bestSh;
        b = bf2f(basec[3 * bestId + 2]) * bestSh;
    } else {
        r = bf2f(bg[0]); g = bf2f(bg[1]); b = bf2f(bg[2]);
    }
    int o = p * 3;
    out[o + 0] = f2bf(r);
    out[o + 1] = f2bf(g);
    out[o + 2] = f2bf(b);
}

// ---------------- diagnostic: ws too small -> encode ws MB into the image -------
__global__ __launch_bounds__(256) void k_diag(bfraw* __restrict__ out, float code) {
    out[blockIdx.x * 256 + threadIdx.x] = f2bf(code);
}

extern "C" void kernel_launch(void* const* d_in, const int* in_sizes, int n_in,
                              void* d_out, int out_size, void* d_ws, size_t ws_size,
                              hipStream_t stream) {
    const bfraw* u = (const bfraw*)d_in[0];
    const bfraw* mvps = (const bfraw*)d_in[1];
    const bfraw* light = (const bfraw*)d_in[2];
    const bfraw* bg = (const bfraw*)d_in[3];
    const bfraw* basec = (const bfraw*)d_in[4];
    const int* faces = (const int*)d_in[5];
    int nrows = in_sizes[0] / 3;
    int F = in_sizes[5] / 3;
    bfraw* out = (bfraw*)d_out;

    char* w = (char*)d_ws;
    size_t off = 0;
    auto alloc = [&](size_t bytes) -> void* {
        off = (off + 255) & ~(size_t)255;
        void* p = w + off;
        off += bytes;
        return p;
    };

    float* cst = (float*)alloc(4 * sizeof(float));
    double* psum = (double*)alloc((size_t)RBLOCKS * 3 * sizeof(double));
    float* pmin = (float*)alloc((size_t)RBLOCKS * 3 * sizeof(float));
    float* pmax = (float*)alloc((size_t)RBLOCKS * 3 * sizeof(float));
    float* tcs = (float*)alloc((size_t)F * 8 * sizeof(float));
    uint32_t* tz = (uint32_t*)alloc((size_t)F * sizeof(uint32_t));
    uint32_t* tbox = (uint32_t*)alloc((size_t)F * sizeof(uint32_t));
    uint32_t* tileMask = (uint32_t*)alloc(512 * sizeof(uint32_t));
    uint32_t* tileList = (uint32_t*)alloc((size_t)MAXT * sizeof(uint32_t));
    uint32_t* tileSlot = (uint32_t*)alloc((size_t)NTILE * sizeof(uint32_t));
    uint32_t* numActive = (uint32_t*)alloc(sizeof(uint32_t));
    uint32_t* cellN = (uint32_t*)alloc((size_t)NC * sizeof(uint32_t));
    uint32_t* cellTop = (uint32_t*)alloc((size_t)MAXT * 256 * sizeof(uint32_t));  // 2 MB
    size_t needed = off;  // ~6.5 MB for F=100k

    if (ws_size < needed) {
        // sentinel: encodes ws_size in MB (bf16-representable integers)
        float code = 20000.0f + (float)(ws_size >> 20);
        k_diag<<<(RESN * RESN * 3) / 256, 256, 0, stream>>>(out, code);
        return;
    }

    k_reduce1<<<RBLOCKS, 256, 0, stream>>>(u, nrows, psum, pmin, pmax,
                                           cellN, tileSlot, tileMask, numActive);
    k_reduce2<<<1, 256, 0, stream>>>(psum, pmin, pmax, nrows, cst);
    k_setup<<<(F + 255) / 256, 256, 0, stream>>>(u, faces, mvps, light, cst, F,
                                                 tcs, tz, tbox, tileMask);
    k_tiles<<<1, 256, 0, stream>>>(tileMask, tileList, tileSlot, numActive);
    k_bin<<<MAXT, 256, 0, stream>>>(tbox, tz, tileList, numActive, cellTop, cellN, F);
    k_raster<<<(RESN * RESN) / 256, 256, 0, stream>>>(tcs, tz, tileSlot, cellN,
                                                      cellTop, basec, bg, out, F);
}